// Round 5
// baseline (104.945 us; speedup 1.0000x reference)
//
#include <hip/hip_runtime.h>

#define H 64
#define WPB 4       // waves per block
#define RPW 2       // races per wave -> grid = B/8 = 2048 blocks = 8 blocks/CU (all co-resident)

typedef _Float16 h2 __attribute__((ext_vector_type(2)));
typedef _Float16 __attribute__((may_alias)) f16a;

union U32H2 { unsigned int u; h2 h; };

// ---- wave64 sum via DPP (rocPRIM pattern). Result uniform via readlane(63).
__device__ __forceinline__ float dpp_add(float x, const int ctrl, const int rmask) {
    int y;
    switch (ctrl) {   // builtin requires literal ctrl/masks
    case 0x111: y = __builtin_amdgcn_update_dpp(0, __float_as_int(x), 0x111, 0xf, 0xf, false); break;
    case 0x112: y = __builtin_amdgcn_update_dpp(0, __float_as_int(x), 0x112, 0xf, 0xf, false); break;
    case 0x114: y = __builtin_amdgcn_update_dpp(0, __float_as_int(x), 0x114, 0xf, 0xf, false); break;
    case 0x118: y = __builtin_amdgcn_update_dpp(0, __float_as_int(x), 0x118, 0xf, 0xf, false); break;
    case 0x142: y = __builtin_amdgcn_update_dpp(0, __float_as_int(x), 0x142, 0xa, 0xf, false); break;
    default:    y = __builtin_amdgcn_update_dpp(0, __float_as_int(x), 0x143, 0xc, 0xf, false); break;
    }
    return x + __int_as_float(y);
}
__device__ __forceinline__ float wave_total(float x) {
    x = dpp_add(x, 0x111, 0xf);   // row_shr:1
    x = dpp_add(x, 0x112, 0xf);   // row_shr:2
    x = dpp_add(x, 0x114, 0xf);   // row_shr:4
    x = dpp_add(x, 0x118, 0xf);   // row_shr:8  -> lane15 of each row = row sum
    x = dpp_add(x, 0x142, 0xa);   // row_bcast:15 -> lanes31/63 = half sums
    x = dpp_add(x, 0x143, 0xc);   // row_bcast:31 -> lane63 = total
    return __int_as_float(__builtin_amdgcn_readlane(__float_as_int(x), 63));
}

__global__ __launch_bounds__(WPB * 64)
void prl_fused(const float* __restrict__ scores,
               const int* __restrict__ rankings,
               const int* __restrict__ mask,
               float2* __restrict__ partial,
               unsigned int* __restrict__ counter,
               float* __restrict__ out, int B)
{
    // Per wave, per race: 16 x uint4; group g = horses 4g..4g+3:
    //   .x = half2(s,s) .y = half2(s,s) .z = half2(k,k) .w = half2(k,k)
    __shared__ uint4 smem[WPB][RPW][H / 4];
    __shared__ float wsum[WPB], wcnt[WPB];
    __shared__ unsigned int is_last;

    const int lane   = threadIdx.x & 63;
    const int wv     = threadIdx.x >> 6;
    const int gwave  = blockIdx.x * WPB + wv;
    const int nwaves = gridDim.x * WPB;

    float s[RPW]; int key[RPW];
    #pragma unroll
    for (int it = 0; it < RPW; ++it) {
        const int race = gwave + it * nwaves;
        s[it] = 0.0f; key[it] = 0;
        if (race < B) {
            const int idx = race * H + lane;
            s[it] = scores[idx];
            const int r = rankings[idx];
            const int m = mask[idx];
            key[it] = (m != 0 && r > 0) ? r : 0;
        }
        // wave-private LDS region -> no __syncthreads; same-wave write->read
        // ordering enforced by compiler lgkmcnt waits
        char* wbase = (char*)&smem[wv][it][0];
        const int g = lane >> 2, sl = (lane & 3) * 2;
        *(f16a*)(wbase + g * 16 + sl)     = (_Float16)s[it];
        *(f16a*)(wbase + g * 16 + 8 + sl) = (_Float16)(float)key[it];
    }

    float loc_sum = 0.0f, loc_has = 0.0f;

    #pragma unroll
    for (int it = 0; it < RPW; ++it) {
        const h2 t2   = (h2)(_Float16)(1.0f - s[it]);   // hinge = max(t + s_j, 0)
        const h2 ki2  = (h2)(_Float16)(float)key[it];
        const h2 zero = (h2)(_Float16)0.0f;
        const h2 one  = (h2)(_Float16)1.0f;

        float sumA = 0.0f, sumB = 0.0f;
        h2 cntA = zero, cntB = zero;   // small exact ints in fp16

        #pragma unroll
        for (int g = 0; g < H / 4; ++g) {
            const uint4 q = smem[wv][it][g];   // wave-uniform -> LDS broadcast
            U32H2 ux, uy, uz, uw;
            ux.u = q.x; uy.u = q.y; uz.u = q.z; uw.u = q.w;
            const h2 hA = __builtin_elementwise_max(t2 + ux.h, zero);
            const h2 hB = __builtin_elementwise_max(t2 + uy.h, zero);
            const h2 pA = __builtin_elementwise_min(__builtin_elementwise_max(uz.h - ki2, zero), one);
            const h2 pB = __builtin_elementwise_min(__builtin_elementwise_max(uw.h - ki2, zero), one);
#if __has_builtin(__builtin_amdgcn_fdot2)
            sumA = __builtin_amdgcn_fdot2(hA, pA, sumA, false);
            sumB = __builtin_amdgcn_fdot2(hB, pB, sumB, false);
#else
            sumA += (float)hA.x * (float)pA.x + (float)hA.y * (float)pA.y;
            sumB += (float)hB.x * (float)pB.x + (float)hB.y * (float)pB.y;
#endif
            cntA = cntA + pA;
            cntB = cntB + pB;
        }

        float sum = sumA + sumB;
        const h2 c2 = cntA + cntB;
        float cnt = (float)c2.x + (float)c2.y;
        if (key[it] == 0) { sum = 0.0f; cnt = 0.0f; }   // invalid-i lanes

        const float tsum = wave_total(sum);   // uniform across wave
        const float tcnt = wave_total(cnt);
        if (tcnt > 0.0f) {                    // uniform branch
            loc_sum += tsum / tcnt;
            loc_has += 1.0f;
        }
    }

    // per-block combine
    if (lane == 0) { wsum[wv] = loc_sum; wcnt[wv] = loc_has; }
    __syncthreads();
    if (threadIdx.x == 0) {
        float ps = 0.0f, pc = 0.0f;
        #pragma unroll
        for (int w = 0; w < WPB; ++w) { ps += wsum[w]; pc += wcnt[w]; }
        partial[blockIdx.x] = make_float2(ps, pc);
        __threadfence();                          // publish partial (device scope)
        const unsigned int old = atomicAdd(counter, 1u);
        is_last = (old == gridDim.x - 1) ? 1u : 0u;
    }
    __syncthreads();

    // last block to finish folds all partials and writes the scalar output
    if (is_last) {
        __threadfence();                          // acquire all partials
        float rs = 0.0f, rc = 0.0f;
        #pragma unroll 4
        for (int i = threadIdx.x; i < (int)gridDim.x; i += WPB * 64) {
            const float2 p = partial[i];
            rs += p.x; rc += p.y;
        }
        const float ws = wave_total(rs);
        const float wc = wave_total(rc);
        if (lane == 0) { wsum[wv] = ws; wcnt[wv] = wc; }
        __syncthreads();
        if (threadIdx.x == 0) {
            float ts = 0.0f, tc = 0.0f;
            #pragma unroll
            for (int w = 0; w < WPB; ++w) { ts += wsum[w]; tc += wcnt[w]; }
            out[0] = (tc > 0.0f) ? ts / tc : 0.0f;
        }
    }
}

extern "C" void kernel_launch(void* const* d_in, const int* in_sizes, int n_in,
                              void* d_out, int out_size, void* d_ws, size_t ws_size,
                              hipStream_t stream)
{
    const float* scores   = (const float*)d_in[0];
    const int*   rankings = (const int*)d_in[1];
    const int*   mask     = (const int*)d_in[2];
    const int B = in_sizes[0] / H;

    const int grid = (B + WPB * RPW - 1) / (WPB * RPW);   // 2048 at B=16384

    float2* partial       = (float2*)d_ws;                // grid slots, all written
    unsigned int* counter = (unsigned int*)((char*)d_ws + grid * sizeof(float2));

    hipMemsetAsync(counter, 0, sizeof(unsigned int), stream);   // graph-safe
    prl_fused<<<grid, WPB * 64, 0, stream>>>(scores, rankings, mask,
                                             partial, counter, (float*)d_out, B);
}

// Round 6
// 90.050 us; speedup vs baseline: 1.1654x; 1.1654x over previous
//
#include <hip/hip_runtime.h>

#define H 64
#define WPB 4       // waves per block
#define RPW 2       // races per wave -> grid = B/8 = 2048 blocks = 8 blocks/CU

typedef _Float16 h2 __attribute__((ext_vector_type(2)));
typedef _Float16 __attribute__((may_alias)) f16a;

union U32H2 { unsigned int u; h2 h; };
union PF    { unsigned long long u; float2 f; };

// ---- wave64 sum via DPP (rocPRIM pattern). Result uniform via readlane(63).
__device__ __forceinline__ float dpp_add(float x, const int ctrl, const int rmask) {
    int y;
    switch (ctrl) {   // builtin requires literal ctrl/masks
    case 0x111: y = __builtin_amdgcn_update_dpp(0, __float_as_int(x), 0x111, 0xf, 0xf, false); break;
    case 0x112: y = __builtin_amdgcn_update_dpp(0, __float_as_int(x), 0x112, 0xf, 0xf, false); break;
    case 0x114: y = __builtin_amdgcn_update_dpp(0, __float_as_int(x), 0x114, 0xf, 0xf, false); break;
    case 0x118: y = __builtin_amdgcn_update_dpp(0, __float_as_int(x), 0x118, 0xf, 0xf, false); break;
    case 0x142: y = __builtin_amdgcn_update_dpp(0, __float_as_int(x), 0x142, 0xa, 0xf, false); break;
    default:    y = __builtin_amdgcn_update_dpp(0, __float_as_int(x), 0x143, 0xc, 0xf, false); break;
    }
    return x + __int_as_float(y);
}
__device__ __forceinline__ float wave_total(float x) {
    x = dpp_add(x, 0x111, 0xf);   // row_shr:1
    x = dpp_add(x, 0x112, 0xf);   // row_shr:2
    x = dpp_add(x, 0x114, 0xf);   // row_shr:4
    x = dpp_add(x, 0x118, 0xf);   // row_shr:8  -> lane15 of each row = row sum
    x = dpp_add(x, 0x142, 0xa);   // row_bcast:15 -> lanes31/63 = half sums
    x = dpp_add(x, 0x143, 0xc);   // row_bcast:31 -> lane63 = total
    return __int_as_float(__builtin_amdgcn_readlane(__float_as_int(x), 63));
}

__global__ __launch_bounds__(WPB * 64)
void prl_fused(const float* __restrict__ scores,
               const int* __restrict__ rankings,
               const int* __restrict__ mask,
               unsigned long long* __restrict__ partial,   // packed float2 per block
               unsigned int* __restrict__ counter,
               float* __restrict__ out, int B)
{
    // Per wave, per race: 16 x uint4; group g = horses 4g..4g+3:
    //   .x = half2(s,s) .y = half2(s,s) .z = half2(k,k) .w = half2(k,k)
    __shared__ uint4 smem[WPB][RPW][H / 4];
    __shared__ float wsum[WPB], wcnt[WPB];
    __shared__ unsigned int is_last;

    const int lane   = threadIdx.x & 63;
    const int wv     = threadIdx.x >> 6;
    const int gwave  = blockIdx.x * WPB + wv;
    const int nwaves = gridDim.x * WPB;

    float s[RPW]; int key[RPW];
    #pragma unroll
    for (int it = 0; it < RPW; ++it) {
        const int race = gwave + it * nwaves;
        s[it] = 0.0f; key[it] = 0;
        if (race < B) {
            const int idx = race * H + lane;
            s[it] = scores[idx];
            const int r = rankings[idx];
            const int m = mask[idx];
            key[it] = (m != 0 && r > 0) ? r : 0;
        }
        // wave-private LDS region -> no __syncthreads; same-wave write->read
        // ordering enforced by compiler lgkmcnt waits
        char* wbase = (char*)&smem[wv][it][0];
        const int g = lane >> 2, sl = (lane & 3) * 2;
        *(f16a*)(wbase + g * 16 + sl)     = (_Float16)s[it];
        *(f16a*)(wbase + g * 16 + 8 + sl) = (_Float16)(float)key[it];
    }

    float loc_sum = 0.0f, loc_has = 0.0f;

    #pragma unroll
    for (int it = 0; it < RPW; ++it) {
        const h2 t2   = (h2)(_Float16)(1.0f - s[it]);   // hinge = max(t + s_j, 0)
        const h2 ki2  = (h2)(_Float16)(float)key[it];
        const h2 zero = (h2)(_Float16)0.0f;
        const h2 one  = (h2)(_Float16)1.0f;

        float sumA = 0.0f, sumB = 0.0f;
        h2 cntA = zero, cntB = zero;   // small exact ints in fp16

        #pragma unroll
        for (int g = 0; g < H / 4; ++g) {
            const uint4 q = smem[wv][it][g];   // wave-uniform -> LDS broadcast
            U32H2 ux, uy, uz, uw;
            ux.u = q.x; uy.u = q.y; uz.u = q.z; uw.u = q.w;
            const h2 hA = __builtin_elementwise_max(t2 + ux.h, zero);
            const h2 hB = __builtin_elementwise_max(t2 + uy.h, zero);
            const h2 pA = __builtin_elementwise_min(__builtin_elementwise_max(uz.h - ki2, zero), one);
            const h2 pB = __builtin_elementwise_min(__builtin_elementwise_max(uw.h - ki2, zero), one);
#if __has_builtin(__builtin_amdgcn_fdot2)
            sumA = __builtin_amdgcn_fdot2(hA, pA, sumA, false);
            sumB = __builtin_amdgcn_fdot2(hB, pB, sumB, false);
#else
            sumA += (float)hA.x * (float)pA.x + (float)hA.y * (float)pA.y;
            sumB += (float)hB.x * (float)pB.x + (float)hB.y * (float)pB.y;
#endif
            cntA = cntA + pA;
            cntB = cntB + pB;
        }

        float sum = sumA + sumB;
        const h2 c2 = cntA + cntB;
        float cnt = (float)c2.x + (float)c2.y;
        if (key[it] == 0) { sum = 0.0f; cnt = 0.0f; }   // invalid-i lanes

        const float tsum = wave_total(sum);   // uniform across wave
        const float tcnt = wave_total(cnt);
        if (tcnt > 0.0f) {                    // uniform branch
            loc_sum += tsum / tcnt;
            loc_has += 1.0f;
        }
    }

    // per-block combine
    if (lane == 0) { wsum[wv] = loc_sum; wcnt[wv] = loc_has; }
    __syncthreads();
    if (threadIdx.x == 0) {
        float ps = 0.0f, pc = 0.0f;
        #pragma unroll
        for (int w = 0; w < WPB; ++w) { ps += wsum[w]; pc += wcnt[w]; }
        // Publish partial with a RELAXED agent-scope atomic store (per-op cache
        // bypass -> no buffer_wbl2 L2 flush, unlike __threadfence which cost
        // +40us in R5). Order store->counter with an explicit vmcnt drain of
        // our single 8B store (acked at the coherence point).
        PF p; p.f = make_float2(ps, pc);
        __hip_atomic_store(&partial[blockIdx.x], p.u,
                           __ATOMIC_RELAXED, __HIP_MEMORY_SCOPE_AGENT);
        asm volatile("s_waitcnt vmcnt(0)" ::: "memory");
        const unsigned int old = __hip_atomic_fetch_add(counter, 1u,
                           __ATOMIC_RELAXED, __HIP_MEMORY_SCOPE_AGENT);
        is_last = (old == gridDim.x - 1) ? 1u : 0u;
    }
    __syncthreads();

    // last block to finish folds all partials and writes the scalar output
    if (is_last) {
        float rs = 0.0f, rc = 0.0f;
        #pragma unroll 4
        for (int i = threadIdx.x; i < (int)gridDim.x; i += WPB * 64) {
            PF p;   // relaxed agent load: bypasses this XCD's (stale) L1/L2
            p.u = __hip_atomic_load(&partial[i],
                      __ATOMIC_RELAXED, __HIP_MEMORY_SCOPE_AGENT);
            rs += p.f.x; rc += p.f.y;
        }
        const float ws = wave_total(rs);
        const float wc = wave_total(rc);
        if (lane == 0) { wsum[wv] = ws; wcnt[wv] = wc; }
        __syncthreads();
        if (threadIdx.x == 0) {
            float ts = 0.0f, tc = 0.0f;
            #pragma unroll
            for (int w = 0; w < WPB; ++w) { ts += wsum[w]; tc += wcnt[w]; }
            out[0] = (tc > 0.0f) ? ts / tc : 0.0f;
        }
    }
}

extern "C" void kernel_launch(void* const* d_in, const int* in_sizes, int n_in,
                              void* d_out, int out_size, void* d_ws, size_t ws_size,
                              hipStream_t stream)
{
    const float* scores   = (const float*)d_in[0];
    const int*   rankings = (const int*)d_in[1];
    const int*   mask     = (const int*)d_in[2];
    const int B = in_sizes[0] / H;

    const int grid = (B + WPB * RPW - 1) / (WPB * RPW);   // 2048 at B=16384

    unsigned long long* partial = (unsigned long long*)d_ws;   // grid slots, all written
    unsigned int* counter = (unsigned int*)((char*)d_ws + grid * sizeof(unsigned long long));

    hipMemsetAsync(counter, 0, sizeof(unsigned int), stream);  // graph-safe
    prl_fused<<<grid, WPB * 64, 0, stream>>>(scores, rankings, mask,
                                             partial, counter, (float*)d_out, B);
}

// Round 7
// 71.626 us; speedup vs baseline: 1.4652x; 1.2572x over previous
//
#include <hip/hip_runtime.h>

#define H 64
#define WPB 4       // waves per block
#define RPW 2       // races per wave -> grid = B/8 = 2048 blocks = 8 blocks/CU

typedef _Float16 h2 __attribute__((ext_vector_type(2)));
typedef _Float16 __attribute__((may_alias)) f16a;

union U32H2 { unsigned int u; h2 h; };

// ---- wave64 sum via DPP (rocPRIM pattern). Result uniform via readlane(63).
// old=0 => identity for disabled lanes. ~60 cyc vs ~400+ for shfl chain.
__device__ __forceinline__ float dpp_add(float x, const int ctrl, const int rmask) {
    int y;
    switch (ctrl) {   // builtin requires literal ctrl/masks
    case 0x111: y = __builtin_amdgcn_update_dpp(0, __float_as_int(x), 0x111, 0xf, 0xf, false); break;
    case 0x112: y = __builtin_amdgcn_update_dpp(0, __float_as_int(x), 0x112, 0xf, 0xf, false); break;
    case 0x114: y = __builtin_amdgcn_update_dpp(0, __float_as_int(x), 0x114, 0xf, 0xf, false); break;
    case 0x118: y = __builtin_amdgcn_update_dpp(0, __float_as_int(x), 0x118, 0xf, 0xf, false); break;
    case 0x142: y = __builtin_amdgcn_update_dpp(0, __float_as_int(x), 0x142, 0xa, 0xf, false); break;
    default:    y = __builtin_amdgcn_update_dpp(0, __float_as_int(x), 0x143, 0xc, 0xf, false); break;
    }
    return x + __int_as_float(y);
}
__device__ __forceinline__ float wave_total(float x) {
    x = dpp_add(x, 0x111, 0xf);   // row_shr:1
    x = dpp_add(x, 0x112, 0xf);   // row_shr:2
    x = dpp_add(x, 0x114, 0xf);   // row_shr:4
    x = dpp_add(x, 0x118, 0xf);   // row_shr:8  -> lane15 of each row = row sum
    x = dpp_add(x, 0x142, 0xa);   // row_bcast:15 -> lanes31/63 = half sums
    x = dpp_add(x, 0x143, 0xc);   // row_bcast:31 -> lane63 = total
    return __int_as_float(__builtin_amdgcn_readlane(__float_as_int(x), 63));
}

// NOTE (R5/R6 lesson): do NOT fuse the final reduction via last-block-done.
// Uniform per-block work makes all 2048 blocks finish together; the counter
// atomics serialize on one cacheline (~25us tail) and __threadfence costs an
// L2 writeback (~40us). Two kernels with contention-free stores is fastest.

__global__ __launch_bounds__(WPB * 64)
void prl_races(const float* __restrict__ scores,
               const int* __restrict__ rankings,
               const int* __restrict__ mask,
               float2* __restrict__ partial, int B)
{
    // Per wave, per race: 16 x uint4; group g = horses 4g..4g+3:
    //   .x = half2(s,s) .y = half2(s,s) .z = half2(k,k) .w = half2(k,k)
    __shared__ uint4 smem[WPB][RPW][H / 4];
    __shared__ float wsum[WPB], wcnt[WPB];

    const int lane   = threadIdx.x & 63;
    const int wv     = threadIdx.x >> 6;
    const int gwave  = blockIdx.x * WPB + wv;
    const int nwaves = gridDim.x * WPB;

    float s[RPW]; int key[RPW];
    #pragma unroll
    for (int it = 0; it < RPW; ++it) {
        const int race = gwave + it * nwaves;
        s[it] = 0.0f; key[it] = 0;
        if (race < B) {
            const int idx = race * H + lane;
            s[it] = scores[idx];
            const int r = rankings[idx];
            const int m = mask[idx];
            key[it] = (m != 0 && r > 0) ? r : 0;
        }
        // wave-private LDS region -> no __syncthreads; same-wave write->read
        // ordering enforced by compiler lgkmcnt waits
        char* wbase = (char*)&smem[wv][it][0];
        const int g = lane >> 2, sl = (lane & 3) * 2;
        *(f16a*)(wbase + g * 16 + sl)     = (_Float16)s[it];
        *(f16a*)(wbase + g * 16 + 8 + sl) = (_Float16)(float)key[it];
    }

    float loc_sum = 0.0f, loc_has = 0.0f;

    #pragma unroll
    for (int it = 0; it < RPW; ++it) {
        const h2 t2   = (h2)(_Float16)(1.0f - s[it]);   // hinge = max(t + s_j, 0)
        const h2 ki2  = (h2)(_Float16)(float)key[it];
        const h2 zero = (h2)(_Float16)0.0f;
        const h2 one  = (h2)(_Float16)1.0f;

        float sumA = 0.0f, sumB = 0.0f;
        h2 cntA = zero, cntB = zero;   // small exact ints in fp16

        #pragma unroll
        for (int g = 0; g < H / 4; ++g) {
            const uint4 q = smem[wv][it][g];   // wave-uniform -> LDS broadcast
            U32H2 ux, uy, uz, uw;
            ux.u = q.x; uy.u = q.y; uz.u = q.z; uw.u = q.w;
            const h2 hA = __builtin_elementwise_max(t2 + ux.h, zero);
            const h2 hB = __builtin_elementwise_max(t2 + uy.h, zero);
            const h2 pA = __builtin_elementwise_min(__builtin_elementwise_max(uz.h - ki2, zero), one);
            const h2 pB = __builtin_elementwise_min(__builtin_elementwise_max(uw.h - ki2, zero), one);
#if __has_builtin(__builtin_amdgcn_fdot2)
            sumA = __builtin_amdgcn_fdot2(hA, pA, sumA, false);
            sumB = __builtin_amdgcn_fdot2(hB, pB, sumB, false);
#else
            sumA += (float)hA.x * (float)pA.x + (float)hA.y * (float)pA.y;
            sumB += (float)hB.x * (float)pB.x + (float)hB.y * (float)pB.y;
#endif
            cntA = cntA + pA;
            cntB = cntB + pB;
        }

        float sum = sumA + sumB;
        const h2 c2 = cntA + cntB;
        float cnt = (float)c2.x + (float)c2.y;
        if (key[it] == 0) { sum = 0.0f; cnt = 0.0f; }   // invalid-i lanes

        const float tsum = wave_total(sum);   // uniform across wave
        const float tcnt = wave_total(cnt);
        if (tcnt > 0.0f) {                    // uniform branch
            loc_sum += tsum / tcnt;
            loc_has += 1.0f;
        }
    }

    // per-block combine (contention-free: one plain store per block)
    if (lane == 0) { wsum[wv] = loc_sum; wcnt[wv] = loc_has; }
    __syncthreads();
    if (threadIdx.x == 0) {
        float ps = 0.0f, pc = 0.0f;
        #pragma unroll
        for (int w = 0; w < WPB; ++w) { ps += wsum[w]; pc += wcnt[w]; }
        partial[blockIdx.x] = make_float2(ps, pc);
    }
}

__global__ __launch_bounds__(512)
void prl_reduce(const float2* __restrict__ partial, float* __restrict__ out, int n)
{
    __shared__ float ss[8], sc[8];
    const int lane = threadIdx.x & 63;
    const int wv   = threadIdx.x >> 6;

    float s = 0.0f, c = 0.0f;
    #pragma unroll 4
    for (int i = threadIdx.x; i < n; i += 512) {   // 4 independent loads at n=2048
        const float2 p = partial[i];
        s += p.x; c += p.y;
    }
    const float ws = wave_total(s);
    const float wc = wave_total(c);
    if (lane == 0) { ss[wv] = ws; sc[wv] = wc; }
    __syncthreads();
    if (threadIdx.x == 0) {
        float ts = 0.0f, tc = 0.0f;
        #pragma unroll
        for (int w = 0; w < 8; ++w) { ts += ss[w]; tc += sc[w]; }
        out[0] = (tc > 0.0f) ? ts / tc : 0.0f;
    }
}

extern "C" void kernel_launch(void* const* d_in, const int* in_sizes, int n_in,
                              void* d_out, int out_size, void* d_ws, size_t ws_size,
                              hipStream_t stream)
{
    const float* scores   = (const float*)d_in[0];
    const int*   rankings = (const int*)d_in[1];
    const int*   mask     = (const int*)d_in[2];
    const int B = in_sizes[0] / H;

    float2* partial = (float2*)d_ws;   // one slot per block, all written

    const int grid = (B + WPB * RPW - 1) / (WPB * RPW);   // 2048 at B=16384
    prl_races<<<grid, WPB * 64, 0, stream>>>(scores, rankings, mask, partial, B);
    prl_reduce<<<1, 512, 0, stream>>>(partial, (float*)d_out, grid);
}